// Round 4
// baseline (277.772 us; speedup 1.0000x reference)
//
#include <hip/hip_runtime.h>
#include <hip/hip_bf16.h>
#include <math.h>

#define NN 10000

typedef __attribute__((ext_vector_type(4))) float f32x4;
typedef __attribute__((ext_vector_type(8))) short short8v;

__device__ __forceinline__ short f2bf(float f) {
  union { float f; unsigned u; } v; v.f = f;
  unsigned u = v.u + 0x7FFFu + ((v.u >> 16) & 1u);  // RNE
  return (short)(u >> 16);
}
__device__ __forceinline__ float bf2f(unsigned short h) {
  union { unsigned u; float f; } v; v.u = ((unsigned)h) << 16;
  return v.f;
}
__device__ __forceinline__ float artanh_(float xx) {
  xx = fminf(fmaxf(xx, -1.f + 1e-7f), 1.f - 1e-7f);
  return atanhf(xx);
}
__device__ __forceinline__ void proj16(float* v) {
  float s = 0.f;
#pragma unroll
  for (int i = 0; i < 16; ++i) s += v[i] * v[i];
  float n = fmaxf(sqrtf(s), 1e-15f);
  const float mxn = 1.0f - 4e-3f;
  if (n > mxn) {
    float sc = mxn / n;
#pragma unroll
    for (int i = 0; i < 16; ++i) v[i] *= sc;
  }
}
__device__ __forceinline__ short8v cvt8(const float4& u, const float4& w) {
  union { __hip_bfloat162 h; unsigned u32; } c0, c1, c2, c3;
  c0.h = __float22bfloat162_rn(make_float2(u.x, u.y));
  c1.h = __float22bfloat162_rn(make_float2(u.z, u.w));
  c2.h = __float22bfloat162_rn(make_float2(w.x, w.y));
  c3.h = __float22bfloat162_rn(make_float2(w.z, w.w));
  union { unsigned v[4]; short8v s; } r;
  r.v[0] = c0.u32; r.v[1] = c1.u32; r.v[2] = c2.u32; r.v[3] = c3.u32;
  return r.s;
}

// ---------------- K1: pass over x -> rhs (both branches) + partial a; zero PB tails ----------------
__global__ __launch_bounds__(192) void k_attn1(
    const float* __restrict__ x,
    const float* __restrict__ U1a, const float* __restrict__ U3a,
    const float* __restrict__ U1b, const float* __restrict__ U3b,
    float* __restrict__ rhsA, float* __restrict__ rhsB,
    float* __restrict__ partAa, float* __restrict__ partAb,
    unsigned short* __restrict__ PB) {
  __shared__ float xs[16 * 193];
  int tid = threadIdx.x;
  int f_ = tid / 12, t_ = tid - f_ * 12;
  int s_ = tid >> 4, nl_ = tid & 15;
  // zero PB pads: (a) frag-step 312 lanes kq>=2 (shorts [256,512) of each frag),
  //               (b) the whole extra frag-step 313 (BK=64 padding).
  if (blockIdx.x == 79) {
    for (int i = tid; i < 3072 + 6144; i += 192) {
      if (i < 3072) {
        int tt = i >> 8, q = i & 255;
        PB[(size_t)(312 * 12 + tt) * 512 + 256 + q] = 0;
      } else {
        PB[(size_t)313 * 12 * 512 + (i - 3072)] = 0;
      }
    }
  }
  float paa = 0.f, pab = 0.f;
  for (int tb = blockIdx.x; tb < 625; tb += 80) {
    int n0 = tb * 16;
    for (int i = tid; i < 16 * 192; i += 192) {
      int a = i / 192, j = i - a * 192;
      xs[a * 193 + j] = x[(size_t)(n0 + a) * 192 + j];
    }
    __syncthreads();
    float ra = 0.f, rb = 0.f;
#pragma unroll
    for (int f = 0; f < 16; ++f) {
      float xv = xs[nl_ * 193 + f * 12 + s_];
      ra += xv * U3a[f];
      rb += xv * U3b[f];
    }
    rhsA[s_ * NN + n0 + nl_] = ra;
    rhsB[s_ * NN + n0 + nl_] = rb;
#pragma unroll
    for (int nl = 0; nl < 16; ++nl) {
      float xv = xs[nl * 193 + f_ * 12 + t_];
      paa += xv * U1a[n0 + nl];
      pab += xv * U1b[n0 + nl];
    }
    __syncthreads();
  }
  partAa[blockIdx.x * 192 + tid] = paa;
  partAb[blockIdx.x * 192 + tid] = pab;
}

// ---------------- K2: M[f,s] partials = sum_n U2[f,n]*rhs[n,s] ----------------
__global__ __launch_bounds__(192) void k_attn2(
    const float* __restrict__ U2a, const float* __restrict__ U2b,
    const float* __restrict__ rhsA, const float* __restrict__ rhsB,
    float* __restrict__ partMa, float* __restrict__ partMb) {
  int tid = threadIdx.x;
  int f = tid / 12, s = tid - f * 12;
  int nA = blockIdx.x * 250, nE = nA + 250;
  float ma = 0.f, mb = 0.f;
  for (int n = nA; n < nE; ++n) {
    ma += U2a[f * NN + n] * rhsA[s * NN + n];
    mb += U2b[f * NN + n] * rhsB[s * NN + n];
  }
  partMa[blockIdx.x * 192 + tid] = ma;
  partMb[blockIdx.x * 192 + tid] = mb;
}

// ---------------- K3: reduce partials, product, E, softmax -> tA (both) ----------------
__global__ __launch_bounds__(192) void k_attn3(
    const float* __restrict__ partAa, const float* __restrict__ partAb,
    const float* __restrict__ partMa, const float* __restrict__ partMb,
    const float* __restrict__ beA, const float* __restrict__ VeA,
    const float* __restrict__ beB, const float* __restrict__ VeB,
    float* __restrict__ tAa, float* __restrict__ tAb) {
  __shared__ float aa[192], ab[192], Ma[192], Mb[192];
  __shared__ float spA[144], spB[144], EA[144], EB[144];
  int tid = threadIdx.x;
  float s1 = 0.f, s2 = 0.f, s3 = 0.f, s4 = 0.f;
  for (int b = 0; b < 80; ++b) { s1 += partAa[b * 192 + tid]; s2 += partAb[b * 192 + tid]; }
  for (int b = 0; b < 40; ++b) { s3 += partMa[b * 192 + tid]; s4 += partMb[b * 192 + tid]; }
  aa[tid] = s1; ab[tid] = s2; Ma[tid] = s3; Mb[tid] = s4;
  __syncthreads();
  if (tid < 144) {
    int j = tid / 12, s = tid - j * 12;
    float pa = 0.f, pb = 0.f;
#pragma unroll
    for (int f = 0; f < 16; ++f) {
      pa += aa[f * 12 + j] * Ma[f * 12 + s];
      pb += ab[f * 12 + j] * Mb[f * 12 + s];
    }
    spA[tid] = 1.f / (1.f + expf(-(pa + beA[tid])));
    spB[tid] = 1.f / (1.f + expf(-(pb + beB[tid])));
  }
  __syncthreads();
  if (tid < 144) {
    int i = tid / 12, s = tid - i * 12;
    float ea = 0.f, eb = 0.f;
#pragma unroll
    for (int j = 0; j < 12; ++j) {
      ea += VeA[i * 12 + j] * spA[j * 12 + s];
      eb += VeB[i * 12 + j] * spB[j * 12 + s];
    }
    EA[tid] = ea; EB[tid] = eb;
  }
  __syncthreads();
  if (tid < 144) {
    int s = tid % 12;
    float ma = -1e30f, mb = -1e30f;
#pragma unroll
    for (int k = 0; k < 12; ++k) { ma = fmaxf(ma, EA[k * 12 + s]); mb = fmaxf(mb, EB[k * 12 + s]); }
    float da = 0.f, db = 0.f;
#pragma unroll
    for (int k = 0; k < 12; ++k) { da += expf(EA[k * 12 + s] - ma); db += expf(EB[k * 12 + s] - mb); }
    tAa[tid] = expf(EA[tid] - ma) / da;
    tAb[tid] = expf(EB[tid] - mb) / db;
  }
}

// ---------------- K4: per-node x_tat + conv (both) + hyperbolic -> PB (lane-ordered B frags), outF ----------------
__global__ __launch_bounds__(192) void k_node(
    const float* __restrict__ x,
    const float* __restrict__ tAa_g, const float* __restrict__ tAb_g,
    const float* __restrict__ w1g, const float* __restrict__ b1g,
    const float* __restrict__ w2g, const float* __restrict__ b2g,
    const float* __restrict__ hwg, const float* __restrict__ hbg,
    float* __restrict__ outF, unsigned short* __restrict__ PB) {
  __shared__ float xs[16 * 193], tbuf[16 * 193];
  __shared__ float tAa[144], tAb[144], w1[768], w2[768];
  __shared__ float cb1[16], cb2[16], hw[256], hbr[16];
  int tid = threadIdx.x;
  int nl = tid & 15, tt = tid >> 4;
  int n0 = blockIdx.x * 16;
  for (int i = tid; i < 144; i += 192) { tAa[i] = tAa_g[i]; tAb[i] = tAb_g[i]; }
  for (int i = tid; i < 768; i += 192) { w1[i] = w1g[i]; w2[i] = w2g[i]; }
  for (int i = tid; i < 256; i += 192) hw[i] = hwg[i];
  if (tid < 16) { cb1[tid] = b1g[tid]; cb2[tid] = b2g[tid]; hbr[tid] = hbg[tid]; }
  for (int i = tid; i < 16 * 192; i += 192) {
    int a = i / 192, j = i - a * 192;
    xs[a * 193 + j] = x[(size_t)(n0 + a) * 192 + j];
  }
  __syncthreads();

  float z[16];
  // ======== branch b (second attention -> conv2 -> final_output) ========
#pragma unroll
  for (int f = 0; f < 16; ++f) {
    float v = 0.f;
#pragma unroll
    for (int s = 0; s < 12; ++s) v += xs[nl * 193 + f * 12 + s] * tAb[s * 12 + tt];
    tbuf[nl * 193 + f * 12 + tt] = v;
  }
  __syncthreads();
#pragma unroll
  for (int o = 0; o < 16; ++o) z[o] = cb2[o];
#pragma unroll
  for (int k = 0; k < 3; ++k) {
    int t2 = tt + k - 1;
    if (t2 >= 0 && t2 < 12) {
#pragma unroll
      for (int i = 0; i < 16; ++i) {
        float xv = tbuf[nl * 193 + i * 12 + t2];
#pragma unroll
        for (int o = 0; o < 16; ++o) z[o] += xv * w2[o * 48 + i * 3 + k];
      }
    }
  }
  {
    float* op = outF + (size_t)tt * (NN * 16) + (size_t)(n0 + nl) * 16;
#pragma unroll
    for (int o = 0; o < 16; ++o) op[o] = z[o];
  }
  __syncthreads();

  // ======== branch a (first attention -> conv1 -> hyperbolic -> xt) ========
#pragma unroll
  for (int f = 0; f < 16; ++f) {
    float v = 0.f;
#pragma unroll
    for (int s = 0; s < 12; ++s) v += xs[nl * 193 + f * 12 + s] * tAa[s * 12 + tt];
    tbuf[nl * 193 + f * 12 + tt] = v;
  }
  __syncthreads();
#pragma unroll
  for (int o = 0; o < 16; ++o) z[o] = cb1[o];
#pragma unroll
  for (int k = 0; k < 3; ++k) {
    int t2 = tt + k - 1;
    if (t2 >= 0 && t2 < 12) {
#pragma unroll
      for (int i = 0; i < 16; ++i) {
        float xv = tbuf[nl * 193 + i * 12 + t2];
#pragma unroll
        for (int o = 0; o < 16; ++o) z[o] += xv * w1[o * 48 + i * 3 + k];
      }
    }
  }
  // x_hyp = proj(expmap0(z))
  float nz = 0.f;
#pragma unroll
  for (int i = 0; i < 16; ++i) nz += z[i] * z[i];
  nz = fmaxf(sqrtf(nz), 1e-15f);
  float sc0 = tanhf(nz) / nz;
#pragma unroll
  for (int i = 0; i < 16; ++i) z[i] *= sc0;
  proj16(z);
  // mobius_matvec(hgc_w, x_hyp)
  float xn = 0.f;
#pragma unroll
  for (int i = 0; i < 16; ++i) xn += z[i] * z[i];
  xn = fmaxf(sqrtf(xn), 1e-15f);
  float mx[16];
#pragma unroll
  for (int d = 0; d < 16; ++d) {
    float v = 0.f;
#pragma unroll
    for (int f = 0; f < 16; ++f) v += z[f] * hw[d * 16 + f];
    mx[d] = v;
  }
  float mxr = 0.f;
#pragma unroll
  for (int d = 0; d < 16; ++d) mxr += mx[d] * mx[d];
  mxr = sqrtf(mxr);
  float mxn = fmaxf(mxr, 1e-15f);
  float rs = tanhf(mxn / xn * artanh_(xn)) / mxn;
  if (mxr == 0.f) rs = 0.f;
#pragma unroll
  for (int d = 0; d < 16; ++d) mx[d] *= rs;
  proj16(mx);
  // hyp_b = proj(expmap0(hgc_b))
  float hb[16];
  float bn = 0.f;
#pragma unroll
  for (int i = 0; i < 16; ++i) { hb[i] = hbr[i]; bn += hb[i] * hb[i]; }
  bn = fmaxf(sqrtf(bn), 1e-15f);
  float sb = tanhf(bn) / bn;
#pragma unroll
  for (int i = 0; i < 16; ++i) hb[i] *= sb;
  proj16(hb);
  // res = proj(mobius_add(mx, hb))
  float x2 = 0.f, y2 = 0.f, xy = 0.f;
#pragma unroll
  for (int i = 0; i < 16; ++i) { x2 += mx[i] * mx[i]; y2 += hb[i] * hb[i]; xy += mx[i] * hb[i]; }
  float ca = 1.f + 2.f * xy + y2;
  float cbv = 1.f - x2;
  float den = fmaxf(1.f + 2.f * xy + x2 * y2, 1e-15f);
#pragma unroll
  for (int i = 0; i < 16; ++i) mx[i] = (ca * mx[i] + cbv * hb[i]) / den;
  proj16(mx);
  // xt = logmap0(res) -> PB in MFMA lane order:
  // PB[frag*512 + lane*8 + j] = B[k=(lane>>4)*8+j][col=lane&15]
  float pn = 0.f;
#pragma unroll
  for (int i = 0; i < 16; ++i) pn += mx[i] * mx[i];
  pn = fmaxf(sqrtf(pn), 1e-15f);
  float sl = artanh_(pn) / pn;
  {
    int nn2 = n0 + nl;
    int s = nn2 >> 5, c = nn2 & 31;
    unsigned short* pp = PB + (size_t)(s * 12 + tt) * 512 + (c >> 3) * 128 + (c & 7);
#pragma unroll
    for (int d = 0; d < 16; ++d)
      pp[d * 8] = (unsigned short)f2bf(mx[d] * sl);
  }
}

// ---------------- K5: sup = adj @ xt (bf16 MFMA, BK=64, 4 waves x 32 rows, LDS dbuf B, NC=4) ----------------
// blockIdx = rt*4 + bc; rows 128/block; K double-steps t in [bc*40, min(157,bc*40+40))
__global__ __launch_bounds__(256, 2) void k_gemm(
    const float* __restrict__ adj, const unsigned short* __restrict__ PB,
    unsigned short* __restrict__ partC) {
  __shared__ unsigned short sB[2][2 * 12 * 512];  // 2 x 24KB double buffer (frags 2t,2t+1)
  int bc = blockIdx.x & 3;
  int rt = blockIdx.x >> 2;
  int t0 = bc * 40;
  int t1 = min(157, t0 + 40);
  int tid = threadIdx.x;
  int w = tid >> 6, lane = tid & 63;
  int r0 = lane & 15, kq = lane >> 4;
  int R0 = rt * 128 + w * 32;

  int rA0 = min(R0 + r0, NN - 1);
  int rA1 = min(R0 + 16 + r0, NN - 1);
  const float* pa0 = adj + (size_t)rA0 * NN + kq * 8;
  const float* pa1 = adj + (size_t)rA1 * NN + kq * 8;

  f32x4 acc0[12], acc1[12];
  f32x4 zz = {0.f, 0.f, 0.f, 0.f};
#pragma unroll
  for (int j = 0; j < 12; ++j) { acc0[j] = zz; acc1[j] = zz; }

  short8v stg[6];
  auto LOADB = [&](int t) {  // frags 2t,2t+1 (24KB) -> regs, 6x16B per thread
    const short8v* g = (const short8v*)PB + (size_t)t * 1536 + tid;
#pragma unroll
    for (int c = 0; c < 6; ++c) stg[c] = g[c * 256];
  };
  auto WRITEB = [&](int p) {
    short8v* l = (short8v*)(sB[p]) + tid;
#pragma unroll
    for (int c = 0; c < 6; ++c) l[c * 256] = stg[c];
  };
  // r[0..1]=frag 2t row0, r[2..3]=frag 2t+1 row0, r[4..5]=frag 2t row1, r[6..7]=frag 2t+1 row1
  auto LOADA = [&](int t, float4* r) {
    int fs0 = 2 * t;
    float4 z4 = make_float4(0.f, 0.f, 0.f, 0.f);
    bool ok0 = (fs0 < 312) || (kq < 2);
    bool ok1 = (fs0 + 1 < 312);
    const float4* q0 = (const float4*)(pa0 + (size_t)fs0 * 32);
    const float4* q1 = (const float4*)(pa1 + (size_t)fs0 * 32);
    if (ok0) { r[0] = q0[0]; r[1] = q0[1]; r[4] = q1[0]; r[5] = q1[1]; }
    else     { r[0] = z4;    r[1] = z4;    r[4] = z4;    r[5] = z4;    }
    if (ok1) { r[2] = q0[8]; r[3] = q0[9]; r[6] = q1[8]; r[7] = q1[9]; }
    else     { r[2] = z4;    r[3] = z4;    r[6] = z4;    r[7] = z4;    }
  };
  auto MM = [&](const float4* ra, int p) {
#pragma unroll
    for (int sub = 0; sub < 2; ++sub) {
      short8v a0 = cvt8(ra[sub * 2 + 0], ra[sub * 2 + 1]);
      short8v a1 = cvt8(ra[4 + sub * 2 + 0], ra[4 + sub * 2 + 1]);
      const unsigned short* base = sB[p] + (size_t)sub * 12 * 512;
#pragma unroll
      for (int j = 0; j < 12; ++j) {
        short8v b = *((const short8v*)(base + j * 512) + lane);
        acc0[j] = __builtin_amdgcn_mfma_f32_16x16x32_bf16(a0, b, acc0[j], 0, 0, 0);
        acc1[j] = __builtin_amdgcn_mfma_f32_16x16x32_bf16(a1, b, acc1[j], 0, 0, 0);
      }
    }
  };

  {
    float4 ra0[8], ra1[8];
    LOADB(t0);
    LOADA(t0, ra0);
    WRITEB(0);
    __syncthreads();
    int t = t0, p = 0;
    while (true) {
      int nx = t + 1;
      bool hn = nx < t1;
      if (hn) { LOADB(nx); LOADA(nx, ra1); }
      MM(ra0, p);
      if (hn) WRITEB(p ^ 1);
      __syncthreads();
      p ^= 1; ++t;
      if (t >= t1) break;
      nx = t + 1; hn = nx < t1;
      if (hn) { LOADB(nx); LOADA(nx, ra0); }
      MM(ra1, p);
      if (hn) WRITEB(p ^ 1);
      __syncthreads();
      p ^= 1; ++t;
      if (t >= t1) break;
    }
  }
  // epilogue: D layout col(lane&15)=feature, row(M)=kq*4+r
  size_t cbase = (size_t)bc * ((size_t)NN * 192);
  int drow = kq * 4;
#pragma unroll
  for (int j = 0; j < 12; ++j) {
#pragma unroll
    for (int r = 0; r < 4; ++r) {
      int rw0 = R0 + drow + r;
      int rw1 = R0 + 16 + drow + r;
      if (rw0 < NN)
        partC[cbase + (size_t)rw0 * 192 + j * 16 + r0] = (unsigned short)f2bf(acc0[j][r]);
      if (rw1 < NN)
        partC[cbase + (size_t)rw1 * 192 + j * 16 + r0] = (unsigned short)f2bf(acc1[j][r]);
    }
  }
}

// ---------------- K6: reduce partials + hyperbolic epilogue -> h ----------------
__global__ __launch_bounds__(256) void k_epi(const unsigned short* __restrict__ partC,
                                             float* __restrict__ outH, int NC) {
  int gid = blockIdx.x * 256 + threadIdx.x;
  if (gid >= NN * 12) return;
  int n = gid / 12, t = gid - n * 12;
  float sup[16];
#pragma unroll
  for (int d = 0; d < 16; ++d) sup[d] = 0.f;
  for (int c = 0; c < NC; ++c) {
    const short8v* p8 = (const short8v*)(partC + (size_t)c * (NN * 192) + (size_t)n * 192 + t * 16);
    short8v lo = p8[0], hi = p8[1];
#pragma unroll
    for (int d = 0; d < 8; ++d) sup[d] += bf2f((unsigned short)lo[d]);
#pragma unroll
    for (int d = 0; d < 8; ++d) sup[8 + d] += bf2f((unsigned short)hi[d]);
  }
  // agg = proj(expmap0(sup))
  float nn_ = 0.f;
#pragma unroll
  for (int d = 0; d < 16; ++d) nn_ += sup[d] * sup[d];
  nn_ = fmaxf(sqrtf(nn_), 1e-15f);
  float s0 = tanhf(nn_) / nn_;
#pragma unroll
  for (int d = 0; d < 16; ++d) sup[d] *= s0;
  proj16(sup);
  // relu(logmap0(agg))
  float pn = 0.f;
#pragma unroll
  for (int d = 0; d < 16; ++d) pn += sup[d] * sup[d];
  pn = fmaxf(sqrtf(pn), 1e-15f);
  float sl = artanh_(pn) / pn;
#pragma unroll
  for (int d = 0; d < 16; ++d) sup[d] = fmaxf(sup[d] * sl, 0.f);
  // proj(expmap0(...))
  float un = 0.f;
#pragma unroll
  for (int d = 0; d < 16; ++d) un += sup[d] * sup[d];
  un = fmaxf(sqrtf(un), 1e-15f);
  float se = tanhf(un) / un;
#pragma unroll
  for (int d = 0; d < 16; ++d) sup[d] *= se;
  proj16(sup);
  float* hp = outH + (size_t)n * 192 + t;  // h[n][d][t]
#pragma unroll
  for (int d = 0; d < 16; ++d) hp[d * 12] = sup[d];
}

extern "C" void kernel_launch(void* const* d_in, const int* in_sizes, int n_in,
                              void* d_out, int out_size, void* d_ws, size_t ws_size,
                              hipStream_t stream) {
  const float* x   = (const float*)d_in[0];
  const float* adj = (const float*)d_in[1];
  const float* U1a = (const float*)d_in[2];
  const float* U2a = (const float*)d_in[3];
  const float* U3a = (const float*)d_in[4];
  const float* bea = (const float*)d_in[5];
  const float* Vea = (const float*)d_in[6];
  const float* U1b = (const float*)d_in[7];
  const float* U2b = (const float*)d_in[8];
  const float* U3b = (const float*)d_in[9];
  const float* beb = (const float*)d_in[10];
  const float* Veb = (const float*)d_in[11];
  const float* w1  = (const float*)d_in[12];
  const float* b1  = (const float*)d_in[13];
  const float* w2  = (const float*)d_in[14];
  const float* b2  = (const float*)d_in[15];
  const float* hw  = (const float*)d_in[16];
  const float* hb  = (const float*)d_in[17];
  float* outF = (float*)d_out;
  float* outH = (float*)d_out + 1920000;

  char* ws = (char*)d_ws;
  size_t off = 0;
  auto alloc = [&](size_t bytes) {
    char* p = ws + off;
    off = (off + bytes + 255) & ~(size_t)255;
    return p;
  };
  float* rhsA   = (float*)alloc((size_t)12 * NN * 4);
  float* rhsB   = (float*)alloc((size_t)12 * NN * 4);
  float* partAa = (float*)alloc(80 * 192 * 4);
  float* partAb = (float*)alloc(80 * 192 * 4);
  float* partMa = (float*)alloc(40 * 192 * 4);
  float* partMb = (float*)alloc(40 * 192 * 4);
  float* tAa    = (float*)alloc(144 * 4);
  float* tAb    = (float*)alloc(144 * 4);
  unsigned short* PB = (unsigned short*)alloc((size_t)314 * 12 * 512 * 2);  // +1 zero frag-step
  const int NC = 4;
  unsigned short* partC = (unsigned short*)alloc((size_t)NC * NN * 192 * 2);
  (void)ws_size;

  k_attn1<<<80, 192, 0, stream>>>(x, U1a, U3a, U1b, U3b, rhsA, rhsB, partAa, partAb, PB);
  k_attn2<<<40, 192, 0, stream>>>(U2a, U2b, rhsA, rhsB, partMa, partMb);
  k_attn3<<<1, 192, 0, stream>>>(partAa, partAb, partMa, partMb, bea, Vea, beb, Veb, tAa, tAb);
  k_node<<<625, 192, 0, stream>>>(x, tAa, tAb, w1, b1, w2, b2, hw, hb, outF, PB);
  k_gemm<<<79 * NC, 256, 0, stream>>>(adj, PB, partC);
  k_epi<<<(NN * 12 + 255) / 256, 256, 0, stream>>>(partC, outH, NC);
}

// Round 5
// 263.032 us; speedup vs baseline: 1.0560x; 1.0560x over previous
//
#include <hip/hip_runtime.h>
#include <hip/hip_bf16.h>
#include <math.h>

#define NN 10000

typedef __attribute__((ext_vector_type(4))) float f32x4;
typedef __attribute__((ext_vector_type(8))) short short8v;

__device__ __forceinline__ short f2bf(float f) {
  union { float f; unsigned u; } v; v.f = f;
  unsigned u = v.u + 0x7FFFu + ((v.u >> 16) & 1u);  // RNE
  return (short)(u >> 16);
}
__device__ __forceinline__ float bf2f(unsigned short h) {
  union { unsigned u; float f; } v; v.u = ((unsigned)h) << 16;
  return v.f;
}
__device__ __forceinline__ float artanh_(float xx) {
  xx = fminf(fmaxf(xx, -1.f + 1e-7f), 1.f - 1e-7f);
  return atanhf(xx);
}
__device__ __forceinline__ void proj16(float* v) {
  float s = 0.f;
#pragma unroll
  for (int i = 0; i < 16; ++i) s += v[i] * v[i];
  float n = fmaxf(sqrtf(s), 1e-15f);
  const float mxn = 1.0f - 4e-3f;
  if (n > mxn) {
    float sc = mxn / n;
#pragma unroll
    for (int i = 0; i < 16; ++i) v[i] *= sc;
  }
}
__device__ __forceinline__ short8v cvt8(const float4& u, const float4& w) {
  union { __hip_bfloat162 h; unsigned u32; } c0, c1, c2, c3;
  c0.h = __float22bfloat162_rn(make_float2(u.x, u.y));
  c1.h = __float22bfloat162_rn(make_float2(u.z, u.w));
  c2.h = __float22bfloat162_rn(make_float2(w.x, w.y));
  c3.h = __float22bfloat162_rn(make_float2(w.z, w.w));
  union { unsigned v[4]; short8v s; } r;
  r.v[0] = c0.u32; r.v[1] = c1.u32; r.v[2] = c2.u32; r.v[3] = c3.u32;
  return r.s;
}

// ---------------- K1: pass over x -> rhs (both branches) + partial a; zero PB tails ----------------
__global__ __launch_bounds__(192) void k_attn1(
    const float* __restrict__ x,
    const float* __restrict__ U1a, const float* __restrict__ U3a,
    const float* __restrict__ U1b, const float* __restrict__ U3b,
    float* __restrict__ rhsA, float* __restrict__ rhsB,
    float* __restrict__ partAa, float* __restrict__ partAb,
    unsigned short* __restrict__ PB) {
  __shared__ float xs[16 * 193];
  int tid = threadIdx.x;
  int f_ = tid / 12, t_ = tid - f_ * 12;
  int s_ = tid >> 4, nl_ = tid & 15;
  // zero PB pads: frag-step 312 lanes kq>=2 (shorts [256,512) of each frag)
  if (blockIdx.x == 79) {
    for (int i = tid; i < 3072; i += 192) {
      int tt = i >> 8, q = i & 255;
      PB[(size_t)(312 * 12 + tt) * 512 + 256 + q] = 0;
    }
  }
  float paa = 0.f, pab = 0.f;
  for (int tb = blockIdx.x; tb < 625; tb += 80) {
    int n0 = tb * 16;
    for (int i = tid; i < 16 * 192; i += 192) {
      int a = i / 192, j = i - a * 192;
      xs[a * 193 + j] = x[(size_t)(n0 + a) * 192 + j];
    }
    __syncthreads();
    float ra = 0.f, rb = 0.f;
#pragma unroll
    for (int f = 0; f < 16; ++f) {
      float xv = xs[nl_ * 193 + f * 12 + s_];
      ra += xv * U3a[f];
      rb += xv * U3b[f];
    }
    rhsA[s_ * NN + n0 + nl_] = ra;
    rhsB[s_ * NN + n0 + nl_] = rb;
#pragma unroll
    for (int nl = 0; nl < 16; ++nl) {
      float xv = xs[nl * 193 + f_ * 12 + t_];
      paa += xv * U1a[n0 + nl];
      pab += xv * U1b[n0 + nl];
    }
    __syncthreads();
  }
  partAa[blockIdx.x * 192 + tid] = paa;
  partAb[blockIdx.x * 192 + tid] = pab;
}

// ---------------- K2: M[f,s] partials = sum_n U2[f,n]*rhs[n,s] ----------------
__global__ __launch_bounds__(192) void k_attn2(
    const float* __restrict__ U2a, const float* __restrict__ U2b,
    const float* __restrict__ rhsA, const float* __restrict__ rhsB,
    float* __restrict__ partMa, float* __restrict__ partMb) {
  int tid = threadIdx.x;
  int f = tid / 12, s = tid - f * 12;
  int nA = blockIdx.x * 250, nE = nA + 250;
  float ma = 0.f, mb = 0.f;
  for (int n = nA; n < nE; ++n) {
    ma += U2a[f * NN + n] * rhsA[s * NN + n];
    mb += U2b[f * NN + n] * rhsB[s * NN + n];
  }
  partMa[blockIdx.x * 192 + tid] = ma;
  partMb[blockIdx.x * 192 + tid] = mb;
}

// ---------------- K3: reduce partials, product, E, softmax -> tA (both) ----------------
__global__ __launch_bounds__(192) void k_attn3(
    const float* __restrict__ partAa, const float* __restrict__ partAb,
    const float* __restrict__ partMa, const float* __restrict__ partMb,
    const float* __restrict__ beA, const float* __restrict__ VeA,
    const float* __restrict__ beB, const float* __restrict__ VeB,
    float* __restrict__ tAa, float* __restrict__ tAb) {
  __shared__ float aa[192], ab[192], Ma[192], Mb[192];
  __shared__ float spA[144], spB[144], EA[144], EB[144];
  int tid = threadIdx.x;
  float s1 = 0.f, s2 = 0.f, s3 = 0.f, s4 = 0.f;
  for (int b = 0; b < 80; ++b) { s1 += partAa[b * 192 + tid]; s2 += partAb[b * 192 + tid]; }
  for (int b = 0; b < 40; ++b) { s3 += partMa[b * 192 + tid]; s4 += partMb[b * 192 + tid]; }
  aa[tid] = s1; ab[tid] = s2; Ma[tid] = s3; Mb[tid] = s4;
  __syncthreads();
  if (tid < 144) {
    int j = tid / 12, s = tid - j * 12;
    float pa = 0.f, pb = 0.f;
#pragma unroll
    for (int f = 0; f < 16; ++f) {
      pa += aa[f * 12 + j] * Ma[f * 12 + s];
      pb += ab[f * 12 + j] * Mb[f * 12 + s];
    }
    spA[tid] = 1.f / (1.f + expf(-(pa + beA[tid])));
    spB[tid] = 1.f / (1.f + expf(-(pb + beB[tid])));
  }
  __syncthreads();
  if (tid < 144) {
    int i = tid / 12, s = tid - i * 12;
    float ea = 0.f, eb = 0.f;
#pragma unroll
    for (int j = 0; j < 12; ++j) {
      ea += VeA[i * 12 + j] * spA[j * 12 + s];
      eb += VeB[i * 12 + j] * spB[j * 12 + s];
    }
    EA[tid] = ea; EB[tid] = eb;
  }
  __syncthreads();
  if (tid < 144) {
    int s = tid % 12;
    float ma = -1e30f, mb = -1e30f;
#pragma unroll
    for (int k = 0; k < 12; ++k) { ma = fmaxf(ma, EA[k * 12 + s]); mb = fmaxf(mb, EB[k * 12 + s]); }
    float da = 0.f, db = 0.f;
#pragma unroll
    for (int k = 0; k < 12; ++k) { da += expf(EA[k * 12 + s] - ma); db += expf(EB[k * 12 + s] - mb); }
    tAa[tid] = expf(EA[tid] - ma) / da;
    tAb[tid] = expf(EB[tid] - mb) / db;
  }
}

// ---------------- K4: per-node x_tat + conv (both) + hyperbolic -> PB (lane-ordered B frags), outF ----------------
__global__ __launch_bounds__(192) void k_node(
    const float* __restrict__ x,
    const float* __restrict__ tAa_g, const float* __restrict__ tAb_g,
    const float* __restrict__ w1g, const float* __restrict__ b1g,
    const float* __restrict__ w2g, const float* __restrict__ b2g,
    const float* __restrict__ hwg, const float* __restrict__ hbg,
    float* __restrict__ outF, unsigned short* __restrict__ PB) {
  __shared__ float xs[16 * 193], tbuf[16 * 193];
  __shared__ float tAa[144], tAb[144], w1[768], w2[768];
  __shared__ float cb1[16], cb2[16], hw[256], hbr[16];
  int tid = threadIdx.x;
  int nl = tid & 15, tt = tid >> 4;
  int n0 = blockIdx.x * 16;
  for (int i = tid; i < 144; i += 192) { tAa[i] = tAa_g[i]; tAb[i] = tAb_g[i]; }
  for (int i = tid; i < 768; i += 192) { w1[i] = w1g[i]; w2[i] = w2g[i]; }
  for (int i = tid; i < 256; i += 192) hw[i] = hwg[i];
  if (tid < 16) { cb1[tid] = b1g[tid]; cb2[tid] = b2g[tid]; hbr[tid] = hbg[tid]; }
  for (int i = tid; i < 16 * 192; i += 192) {
    int a = i / 192, j = i - a * 192;
    xs[a * 193 + j] = x[(size_t)(n0 + a) * 192 + j];
  }
  __syncthreads();

  float z[16];
  // ======== branch b (second attention -> conv2 -> final_output) ========
#pragma unroll
  for (int f = 0; f < 16; ++f) {
    float v = 0.f;
#pragma unroll
    for (int s = 0; s < 12; ++s) v += xs[nl * 193 + f * 12 + s] * tAb[s * 12 + tt];
    tbuf[nl * 193 + f * 12 + tt] = v;
  }
  __syncthreads();
#pragma unroll
  for (int o = 0; o < 16; ++o) z[o] = cb2[o];
#pragma unroll
  for (int k = 0; k < 3; ++k) {
    int t2 = tt + k - 1;
    if (t2 >= 0 && t2 < 12) {
#pragma unroll
      for (int i = 0; i < 16; ++i) {
        float xv = tbuf[nl * 193 + i * 12 + t2];
#pragma unroll
        for (int o = 0; o < 16; ++o) z[o] += xv * w2[o * 48 + i * 3 + k];
      }
    }
  }
  {
    float* op = outF + (size_t)tt * (NN * 16) + (size_t)(n0 + nl) * 16;
#pragma unroll
    for (int o = 0; o < 16; ++o) op[o] = z[o];
  }
  __syncthreads();

  // ======== branch a (first attention -> conv1 -> hyperbolic -> xt) ========
#pragma unroll
  for (int f = 0; f < 16; ++f) {
    float v = 0.f;
#pragma unroll
    for (int s = 0; s < 12; ++s) v += xs[nl * 193 + f * 12 + s] * tAa[s * 12 + tt];
    tbuf[nl * 193 + f * 12 + tt] = v;
  }
  __syncthreads();
#pragma unroll
  for (int o = 0; o < 16; ++o) z[o] = cb1[o];
#pragma unroll
  for (int k = 0; k < 3; ++k) {
    int t2 = tt + k - 1;
    if (t2 >= 0 && t2 < 12) {
#pragma unroll
      for (int i = 0; i < 16; ++i) {
        float xv = tbuf[nl * 193 + i * 12 + t2];
#pragma unroll
        for (int o = 0; o < 16; ++o) z[o] += xv * w1[o * 48 + i * 3 + k];
      }
    }
  }
  // x_hyp = proj(expmap0(z))
  float nz = 0.f;
#pragma unroll
  for (int i = 0; i < 16; ++i) nz += z[i] * z[i];
  nz = fmaxf(sqrtf(nz), 1e-15f);
  float sc0 = tanhf(nz) / nz;
#pragma unroll
  for (int i = 0; i < 16; ++i) z[i] *= sc0;
  proj16(z);
  // mobius_matvec(hgc_w, x_hyp)
  float xn = 0.f;
#pragma unroll
  for (int i = 0; i < 16; ++i) xn += z[i] * z[i];
  xn = fmaxf(sqrtf(xn), 1e-15f);
  float mx[16];
#pragma unroll
  for (int d = 0; d < 16; ++d) {
    float v = 0.f;
#pragma unroll
    for (int f = 0; f < 16; ++f) v += z[f] * hw[d * 16 + f];
    mx[d] = v;
  }
  float mxr = 0.f;
#pragma unroll
  for (int d = 0; d < 16; ++d) mxr += mx[d] * mx[d];
  mxr = sqrtf(mxr);
  float mxn = fmaxf(mxr, 1e-15f);
  float rs = tanhf(mxn / xn * artanh_(xn)) / mxn;
  if (mxr == 0.f) rs = 0.f;
#pragma unroll
  for (int d = 0; d < 16; ++d) mx[d] *= rs;
  proj16(mx);
  // hyp_b = proj(expmap0(hgc_b))
  float hb[16];
  float bn = 0.f;
#pragma unroll
  for (int i = 0; i < 16; ++i) { hb[i] = hbr[i]; bn += hb[i] * hb[i]; }
  bn = fmaxf(sqrtf(bn), 1e-15f);
  float sb = tanhf(bn) / bn;
#pragma unroll
  for (int i = 0; i < 16; ++i) hb[i] *= sb;
  proj16(hb);
  // res = proj(mobius_add(mx, hb))
  float x2 = 0.f, y2 = 0.f, xy = 0.f;
#pragma unroll
  for (int i = 0; i < 16; ++i) { x2 += mx[i] * mx[i]; y2 += hb[i] * hb[i]; xy += mx[i] * hb[i]; }
  float ca = 1.f + 2.f * xy + y2;
  float cbv = 1.f - x2;
  float den = fmaxf(1.f + 2.f * xy + x2 * y2, 1e-15f);
#pragma unroll
  for (int i = 0; i < 16; ++i) mx[i] = (ca * mx[i] + cbv * hb[i]) / den;
  proj16(mx);
  // xt = logmap0(res) -> PB in MFMA lane order:
  // PB[frag*512 + lane*8 + j] = B[k=(lane>>4)*8+j][col=lane&15]
  float pn = 0.f;
#pragma unroll
  for (int i = 0; i < 16; ++i) pn += mx[i] * mx[i];
  pn = fmaxf(sqrtf(pn), 1e-15f);
  float sl = artanh_(pn) / pn;
  {
    int nn2 = n0 + nl;
    int s = nn2 >> 5, c = nn2 & 31;
    unsigned short* pp = PB + (size_t)(s * 12 + tt) * 512 + (c >> 3) * 128 + (c & 7);
#pragma unroll
    for (int d = 0; d < 16; ++d)
      pp[d * 8] = (unsigned short)f2bf(mx[d] * sl);
  }
}

// ---------------- K5: sup = adj @ xt (bf16 MFMA, BK=32, global_load_lds dbuf, swizzled A) ----------------
// blockIdx = bc*79 + rt ; 128 rows/block (4 waves x 32) ; K-steps t in [bc*S, min(313,bc*S+S))
__global__ __launch_bounds__(256, 2) void k_gemm(
    const float* __restrict__ adj, const unsigned short* __restrict__ PB,
    unsigned short* __restrict__ partC, int S) {
  __shared__ float sA[2][128 * 32];            // 2 x 16 KB fp32 A tile (swizzled rows)
  __shared__ unsigned short sB[2][12 * 512];   // 2 x 12 KB bf16 B frags (lane order)
  int bc = blockIdx.x / 79;
  int rt = blockIdx.x - bc * 79;
  int t0 = bc * S, t1 = min(313, t0 + S);
  int tid = threadIdx.x;
  int lane = tid & 63, w = tid >> 6;
  int r0 = lane & 15, kq = lane >> 4;
  int R0 = rt * 128 + w * 32;

  // A staging map: thread covers LDS 16B-chunks li16 = c*256+tid (c=0..3)
  // row = li16>>3, within-row byte off = (li16&7)*16, swizzle xa(row) = ((row&3)<<5)|((row&4)<<2)
  int arow[4], aoffF[4];
#pragma unroll
  for (int c = 0; c < 4; ++c) {
    int li = c * 256 + tid;
    int row = li >> 3;
    int off = (li & 7) * 16;
    int xa = ((row & 3) << 5) | ((row & 4) << 2);
    arow[c] = min(rt * 128 + row, NN - 1);
    aoffF[c] = (off ^ xa) >> 2;  // float index within row
  }

  f32x4 acc0[12], acc1[12];
  f32x4 zz = {0.f, 0.f, 0.f, 0.f};
#pragma unroll
  for (int j = 0; j < 12; ++j) { acc0[j] = zz; acc1[j] = zz; }

  auto STAGE = [&](int p, int t) {
    // B frags: 12 KB = 3 rounds of 256 threads x 16B (linear both sides)
    const unsigned short* gb = PB + (size_t)t * 6144;
#pragma unroll
    for (int c = 0; c < 3; ++c) {
      int li = c * 256 + tid;
      __builtin_amdgcn_global_load_lds((const void*)(gb + li * 8),
                                       (void*)(&sB[p][li * 8]), 16, 0, 0);
    }
    // A tile: 16 KB = 4 rounds; source = adj[row][t*32 + aoffF] (clamped), dest linear
#pragma unroll
    for (int c = 0; c < 4; ++c) {
      int li = c * 256 + tid;
      int fo = t * 32 + aoffF[c];
      if (fo >= NN) fo = 0;  // K tail: logical slots multiply zeroed B
      __builtin_amdgcn_global_load_lds((const void*)(adj + (size_t)arow[c] * NN + fo),
                                       (void*)(&sA[p][li * 4]), 16, 0, 0);
    }
  };

  int xr = ((r0 & 3) << 5) | ((r0 & 4) << 2);  // read-side swizzle (same for row r0 and r0+16)
  auto MM = [&](int p) {
    const char* Ab = (const char*)(sA[p]);
    float4 a00 = *(const float4*)(Ab + r0 * 128 + ((kq * 32 + 0) ^ xr));
    float4 a01 = *(const float4*)(Ab + r0 * 128 + ((kq * 32 + 16) ^ xr));
    float4 a10 = *(const float4*)(Ab + (r0 + 16) * 128 + ((kq * 32 + 0) ^ xr));
    float4 a11 = *(const float4*)(Ab + (r0 + 16) * 128 + ((kq * 32 + 16) ^ xr));
    short8v fa0 = cvt8(a00, a01);
    short8v fa1 = cvt8(a10, a11);
    const unsigned short* Bb = sB[p];
#pragma unroll
    for (int j = 0; j < 12; ++j) {
      short8v b = *((const short8v*)(Bb + j * 512) + lane);
      acc0[j] = __builtin_amdgcn_mfma_f32_16x16x32_bf16(fa0, b, acc0[j], 0, 0, 0);
      acc1[j] = __builtin_amdgcn_mfma_f32_16x16x32_bf16(fa1, b, acc1[j], 0, 0, 0);
    }
  };

  if (t0 < t1) {
    STAGE(0, t0);
    __syncthreads();  // drains vmcnt -> buf0 ready
    int p = 0;
    for (int t = t0; t < t1; ++t) {
      if (t + 1 < t1) STAGE(p ^ 1, t + 1);  // issue next-tile DMA before compute
      MM(p);
      __syncthreads();  // one barrier per step (drains DMA for next MM)
      p ^= 1;
    }
  }
  // epilogue: D layout col(lane&15)=feature, row(M)=kq*4+r
  size_t cbase = (size_t)bc * ((size_t)NN * 192);
  int drow = kq * 4;
#pragma unroll
  for (int j = 0; j < 12; ++j) {
#pragma unroll
    for (int r = 0; r < 4; ++r) {
      int rw0 = R0 + drow + r;
      int rw1 = R0 + 16 + drow + r;
      if (rw0 < NN)
        partC[cbase + (size_t)rw0 * 192 + j * 16 + r0] = (unsigned short)f2bf(acc0[j][r]);
      if (rw1 < NN)
        partC[cbase + (size_t)rw1 * 192 + j * 16 + r0] = (unsigned short)f2bf(acc1[j][r]);
    }
  }
}

// ---------------- K6: reduce partials + hyperbolic epilogue -> h ----------------
__global__ __launch_bounds__(256) void k_epi(const unsigned short* __restrict__ partC,
                                             float* __restrict__ outH, int NC) {
  int gid = blockIdx.x * 256 + threadIdx.x;
  if (gid >= NN * 12) return;
  int n = gid / 12, t = gid - n * 12;
  float sup[16];
#pragma unroll
  for (int d = 0; d < 16; ++d) sup[d] = 0.f;
  for (int c = 0; c < NC; ++c) {
    const short8v* p8 = (const short8v*)(partC + (size_t)c * (NN * 192) + (size_t)n * 192 + t * 16);
    short8v lo = p8[0], hi = p8[1];
#pragma unroll
    for (int d = 0; d < 8; ++d) sup[d] += bf2f((unsigned short)lo[d]);
#pragma unroll
    for (int d = 0; d < 8; ++d) sup[8 + d] += bf2f((unsigned short)hi[d]);
  }
  // agg = proj(expmap0(sup))
  float nn_ = 0.f;
#pragma unroll
  for (int d = 0; d < 16; ++d) nn_ += sup[d] * sup[d];
  nn_ = fmaxf(sqrtf(nn_), 1e-15f);
  float s0 = tanhf(nn_) / nn_;
#pragma unroll
  for (int d = 0; d < 16; ++d) sup[d] *= s0;
  proj16(sup);
  // relu(logmap0(agg))
  float pn = 0.f;
#pragma unroll
  for (int d = 0; d < 16; ++d) pn += sup[d] * sup[d];
  pn = fmaxf(sqrtf(pn), 1e-15f);
  float sl = artanh_(pn) / pn;
#pragma unroll
  for (int d = 0; d < 16; ++d) sup[d] = fmaxf(sup[d] * sl, 0.f);
  // proj(expmap0(...))
  float un = 0.f;
#pragma unroll
  for (int d = 0; d < 16; ++d) un += sup[d] * sup[d];
  un = fmaxf(sqrtf(un), 1e-15f);
  float se = tanhf(un) / un;
#pragma unroll
  for (int d = 0; d < 16; ++d) sup[d] *= se;
  proj16(sup);
  float* hp = outH + (size_t)n * 192 + t;  // h[n][d][t]
#pragma unroll
  for (int d = 0; d < 16; ++d) hp[d * 12] = sup[d];
}

extern "C" void kernel_launch(void* const* d_in, const int* in_sizes, int n_in,
                              void* d_out, int out_size, void* d_ws, size_t ws_size,
                              hipStream_t stream) {
  const float* x   = (const float*)d_in[0];
  const float* adj = (const float*)d_in[1];
  const float* U1a = (const float*)d_in[2];
  const float* U2a = (const float*)d_in[3];
  const float* U3a = (const float*)d_in[4];
  const float* bea = (const float*)d_in[5];
  const float* Vea = (const float*)d_in[6];
  const float* U1b = (const float*)d_in[7];
  const float* U2b = (const float*)d_in[8];
  const float* U3b = (const float*)d_in[9];
  const float* beb = (const float*)d_in[10];
  const float* Veb = (const float*)d_in[11];
  const float* w1  = (const float*)d_in[12];
  const float* b1  = (const float*)d_in[13];
  const float* w2  = (const float*)d_in[14];
  const float* b2  = (const float*)d_in[15];
  const float* hw  = (const float*)d_in[16];
  const float* hb  = (const float*)d_in[17];
  float* outF = (float*)d_out;
  float* outH = (float*)d_out + 1920000;

  char* ws = (char*)d_ws;
  size_t off = 0;
  auto alloc = [&](size_t bytes) {
    char* p = ws + off;
    off = (off + bytes + 255) & ~(size_t)255;
    return p;
  };
  float* rhsA   = (float*)alloc((size_t)12 * NN * 4);
  float* rhsB   = (float*)alloc((size_t)12 * NN * 4);
  float* partAa = (float*)alloc(80 * 192 * 4);
  float* partAb = (float*)alloc(80 * 192 * 4);
  float* partMa = (float*)alloc(40 * 192 * 4);
  float* partMb = (float*)alloc(40 * 192 * 4);
  float* tAa    = (float*)alloc(144 * 4);
  float* tAb    = (float*)alloc(144 * 4);
  unsigned short* PB = (unsigned short*)alloc((size_t)314 * 12 * 512 * 2);
  size_t chunkB = (size_t)NN * 192 * 2;
  size_t avail = (ws_size > off) ? (ws_size - off) : 0;
  int NC = (int)(avail / chunkB);
  if (NC > 8) NC = 8;
  if (NC < 1) NC = 1;
  unsigned short* partC = (unsigned short*)(ws + off);
  int S = (313 + NC - 1) / NC;

  k_attn1<<<80, 192, 0, stream>>>(x, U1a, U3a, U1b, U3b, rhsA, rhsB, partAa, partAb, PB);
  k_attn2<<<40, 192, 0, stream>>>(U2a, U2b, rhsA, rhsB, partMa, partMb);
  k_attn3<<<1, 192, 0, stream>>>(partAa, partAb, partMa, partMb, bea, Vea, beb, Veb, tAa, tAb);
  k_node<<<625, 192, 0, stream>>>(x, tAa, tAb, w1, b1, w2, b2, hw, hb, outF, PB);
  k_gemm<<<79 * NC, 256, 0, stream>>>(adj, PB, partC, S);
  k_epi<<<(NN * 12 + 255) / 256, 256, 0, stream>>>(partC, outH, NC);
}